// Round 11
// baseline (379.250 us; speedup 1.0000x reference)
//
#include <hip/hip_runtime.h>

typedef _Float16 half_t;
typedef _Float16 half8  __attribute__((ext_vector_type(8)));
typedef _Float16 half4v __attribute__((ext_vector_type(4)));
typedef _Float16 half2v __attribute__((ext_vector_type(2)));
typedef float    f32x4  __attribute__((ext_vector_type(4)));
typedef float    f32x2  __attribute__((ext_vector_type(2)));

constexpr int N_NODES = 32768;
constexpr int NPG_    = 512;

#define MFMA16(a, b, c) __builtin_amdgcn_mfma_f32_16x16x32_f16((a), (b), (c), 0, 0, 0)

#if defined(__has_builtin)
#  if __has_builtin(__builtin_amdgcn_cvt_pk_f16_fp8)
#    define HAVE_PK_F16_FP8 1
#  else
#    define HAVE_PK_F16_FP8 0
#  endif
#else
#  define HAVE_PK_F16_FP8 0
#endif

__device__ __forceinline__ void gload_lds16(const half_t* g, half_t* l) {
  __builtin_amdgcn_global_load_lds(
      (const __attribute__((address_space(1))) void*)g,
      (__attribute__((address_space(3))) void*)l, 16, 0, 0);
}

// decode 4 fp8 (one dword) and fma into 2 half2 accumulators with weight p
__device__ __forceinline__ void fp8x4_fma(int wrd, half2v p, half2v* acc) {
#if HAVE_PK_F16_FP8
  half2v lo = __builtin_amdgcn_cvt_pk_f16_fp8((short)(wrd & 0xffff));
  half2v hi = __builtin_amdgcn_cvt_pk_f16_fp8((short)(((unsigned)wrd) >> 16));
#else
  f32x2 flo = __builtin_amdgcn_cvt_pk_f32_fp8(wrd, false);
  f32x2 fhi = __builtin_amdgcn_cvt_pk_f32_fp8(wrd, true);
  half2v lo = {(half_t)flo.x, (half_t)flo.y};
  half2v hi = {(half_t)fhi.x, (half_t)fhi.y};
#endif
  acc[0] += p * lo;
  acc[1] += p * hi;
}

// ---------------- CSR build ----------------
// R7: histogram folded into k_convert tail.
// R9: scatter atomics eliminated via per-edge rank (histogram atomic's return).
// R10: scan1+scan23 merged into ONE kernel — each block redundantly computes
//      all 128 chunk sums (coalesced int4 loads + wave reduce), scans them in
//      LDS, then does its local 256-scan + rowptr/self-loop writes.
__global__ __launch_bounds__(256) void k_scan_all(
    const int* __restrict__ deg, int* __restrict__ rowptr, int* __restrict__ col)
{
  __shared__ int cs[128];
  __shared__ int lsc[256];
  int t = threadIdx.x;
  int w = t >> 6, lane = t & 63;

  // phase 1: chunk sums (chunk = 256 nodes). thread t's int4 at deg4[t+256*i]
  // lies wholly in chunk 4*i + (t>>6); wave w reduces chunk 4*i+w.
  const int4* deg4 = (const int4*)deg;
  #pragma unroll 4
  for (int i = 0; i < 32; i++) {
    int4 v = deg4[t + 256 * i];
    int s = v.x + v.y + v.z + v.w + 4;     // +4: self-loops of the 4 nodes
    s += __shfl_xor(s, 1);  s += __shfl_xor(s, 2);  s += __shfl_xor(s, 4);
    s += __shfl_xor(s, 8);  s += __shfl_xor(s, 16); s += __shfl_xor(s, 32);
    if (lane == 0) cs[4 * i + w] = s;
  }
  __syncthreads();
  // phase 2: inclusive scan of the 128 chunk sums
  for (int off = 1; off < 128; off <<= 1) {
    int add = (t < 128 && t >= off) ? cs[t - off] : 0;
    __syncthreads();
    if (t < 128) cs[t] += add;
    __syncthreads();
  }
  // phase 3: local scan of this block's chunk + writes
  int b = blockIdx.x;
  int i = b * 256 + t;
  int v = deg[i] + 1;                      // +1 = self-loop
  lsc[t] = v;
  __syncthreads();
  int acc = v;
  for (int off = 1; off < 256; off <<= 1) {
    int add = (t >= off) ? lsc[t - off] : 0;
    __syncthreads();
    acc += add;
    lsc[t] = acc;
    __syncthreads();
  }
  int bo = (b == 0) ? 0 : cs[b - 1];
  int rp = bo + acc - v;                   // exclusive prefix
  rowptr[i] = rp;
  col[rp] = i;                             // self-loop at slot 0
  if (b == 127 && t == 255) rowptr[N_NODES] = cs[127];
}

// ---------------- fused conversions + edge histogram + rank (R9) ----------------
__global__ void k_convert(
    const float* __restrict__ x,  half_t* __restrict__ x_h,
    const float* __restrict__ W1, half_t* __restrict__ W1t,
    const float* __restrict__ W2, half_t* __restrict__ W2t,
    const float* __restrict__ W3, half_t* __restrict__ W3t,
    const float* __restrict__ Wi, half_t* __restrict__ Wi_h,
    const float* __restrict__ Wo, half_t* __restrict__ Wo_h,
    const int* __restrict__ dst, int* __restrict__ deg,
    int* __restrict__ rank, int E)
{
  int bid = blockIdx.x, t = threadIdx.x;
  if (bid < 4096) {
    int i = bid * 256 + t;
    float4 v = *(const float4*)(x + (size_t)i * 4);
    half4v h = {(half_t)v.x, (half_t)v.y, (half_t)v.z, (half_t)v.w};
    *(half4v*)(x_h + (size_t)i * 4) = h;
  } else if (bid < 4224) {
    int i = (bid - 4096) * 256 + t;
    int o = i >> 7, k = i & 127;
    W1t[i] = (half_t)W1[k * 256 + o];
  } else if (bid < 4480) {
    int i = (bid - 4224) * 256 + t;
    int o = i >> 8, k = i & 255;
    W2t[i] = (half_t)W2[k * 256 + o];
  } else if (bid < 4608) {
    int i = (bid - 4480) * 256 + t;
    int o = i >> 8, k = i & 255;
    W3t[i] = (half_t)W3[k * 128 + o];
  } else if (bid < 4800) {
    int i = (bid - 4608) * 256 + t;
    float4 v = *(const float4*)(Wi + (size_t)i * 4);
    half4v h = {(half_t)v.x, (half_t)v.y, (half_t)v.z, (half_t)v.w};
    *(half4v*)(Wi_h + (size_t)i * 4) = h;
  } else if (bid < 4864) {
    int i = (bid - 4800) * 256 + t;
    float4 v = *(const float4*)(Wo + (size_t)i * 4);
    half4v h = {(half_t)v.x, (half_t)v.y, (half_t)v.z, (half_t)v.w};
    *(half4v*)(Wo_h + (size_t)i * 4) = h;
  } else {
    // edge histogram; atomic return value = this edge's rank in its segment
    int i = (bid - 4864) * 256 + t;
    if (i < E) rank[i] = atomicAdd(&deg[dst[i]], 1);
  }
}

// ---------------- residency-first GEMM body (tile 128x64, BK=64) ----------------
__device__ __forceinline__ void gemm_wide_body(
    int bx, int by,
    const half_t* __restrict__ A, const half_t* __restrict__ Bt,
    const float* __restrict__ bias, int bias_per_row,
    half_t* __restrict__ outh, int Nc, int K,
    half_t* As, half_t* Bs)
{
  int w = threadIdx.x >> 6, lane = threadIdx.x & 63;
  int r = lane & 15, q = lane >> 4;
  int m0 = by * 128, n0 = bx * 64;
  int mh = (w & 1) * 64, nh = (w >> 1) * 32;
  f32x4 acc[4][2];
  #pragma unroll
  for (int i = 0; i < 4; i++)
    #pragma unroll
    for (int j = 0; j < 2; j++) acc[i][j] = f32x4{0.f, 0.f, 0.f, 0.f};

  int srow = lane >> 3, sc = lane & 7;

  for (int k0 = 0; k0 < K; k0 += 64) {
    __syncthreads();
    #pragma unroll
    for (int i = 0; i < 4; i++) {
      int R0 = w * 32 + i * 8;
      int row = R0 + srow;
      int cg = sc ^ (row & 7);
      gload_lds16(A + (size_t)(m0 + row) * K + k0 + cg * 8, &As[R0 * 64]);
    }
    #pragma unroll
    for (int i = 0; i < 2; i++) {
      int R0 = w * 16 + i * 8;
      int row = R0 + srow;
      int cg = sc ^ (row & 7);
      gload_lds16(Bt + (size_t)(n0 + row) * K + k0 + cg * 8, &Bs[R0 * 64]);
    }
    __syncthreads();
    #pragma unroll
    for (int kk = 0; kk < 2; kk++) {
      half8 af[4], bf[2];
      #pragma unroll
      for (int t = 0; t < 4; t++) {
        int rr = mh + t * 16 + r;
        af[t] = *(const half8*)&As[rr * 64 + (((kk * 4 + q) ^ (rr & 7)) << 3)];
      }
      #pragma unroll
      for (int t = 0; t < 2; t++) {
        int rr = nh + t * 16 + r;
        bf[t] = *(const half8*)&Bs[rr * 64 + (((kk * 4 + q) ^ (rr & 7)) << 3)];
      }
      #pragma unroll
      for (int ti = 0; ti < 4; ti++)
        #pragma unroll
        for (int tj = 0; tj < 2; tj++)
          acc[ti][tj] = MFMA16(af[ti], bf[tj], acc[ti][tj]);
    }
  }

  #pragma unroll
  for (int tj = 0; tj < 2; tj++) {
    int colc = n0 + nh + tj * 16 + r;
    float bc = bias_per_row ? 0.f : bias[colc];
    #pragma unroll
    for (int ti = 0; ti < 4; ti++) {
      #pragma unroll
      for (int i = 0; i < 4; i++) {
        int row = m0 + mh + ti * 16 + q * 4 + i;
        float bv = bias_per_row ? bias[row] : bc;
        outh[(size_t)row * Nc + colc] = (half_t)(acc[ti][tj][i] + bv);
      }
    }
  }
}

// merged QK-projection (2048 blocks) + V^T-projection (1024 blocks)
__global__ __launch_bounds__(256) void k_gemm_qkv2(
    const half_t* __restrict__ x2, const half_t* __restrict__ Wi_h,
    const float* __restrict__ bi,
    half_t* __restrict__ qk, half_t* __restrict__ vt)
{
  __shared__ __align__(16) half_t As[128 * 64];
  __shared__ __align__(16) half_t Bs[64 * 64];
  int id = blockIdx.x;
  if (id < 2048) {
    gemm_wide_body(id & 7, id >> 3, x2, Wi_h, bi, 0, qk, 512, 256, As, Bs);
  } else {
    int id2 = id - 2048;
    gemm_wide_body(id2 & 511, id2 >> 9, Wi_h + 512 * 256, x2, bi + 512, 1,
                   vt, 32768, 256, As, Bs);
  }
}

// ---------------- residency-first GAT GEMM: 128x64 tile + fused es/ed ----------------
// FUSE_SCAT (R9): extra blockIdx.y >= N/128 blocks perform the atomic-free
// rank-based edge scatter (independent of the GEMM; overlapped).
template<int NC, int H, bool FP8O, bool FUSE_SCAT>
__global__ __launch_bounds__(256) void k_gemm_gat(
    const half_t* __restrict__ A, const half_t* __restrict__ Bt,
    half_t* __restrict__ outh, unsigned char* __restrict__ out8, int K,
    const float* __restrict__ aS, const float* __restrict__ aD,
    float* __restrict__ es, float* __restrict__ ed,
    const int* __restrict__ srcE, const int* __restrict__ dstE,
    const int* __restrict__ rowptr, const int* __restrict__ rank,
    int* __restrict__ col, int E)
{
  __shared__ __align__(16) half_t As[128 * 64];
  __shared__ __align__(16) half_t Bs[64 * 64];
  __shared__ float sRed[2][4][64];

  if (FUSE_SCAT && (int)blockIdx.y >= N_NODES / 128) {
    int i = (((int)blockIdx.y - N_NODES / 128) * 4 + (int)blockIdx.x) * 256
            + (int)threadIdx.x;
    if (i < E) {
      int d = dstE[i];
      col[rowptr[d] + 1 + rank[i]] = srcE[i];   // +1: self-loop at slot 0
    }
    return;
  }

  int w = threadIdx.x >> 6, lane = threadIdx.x & 63;
  int cc = lane & 15, qq = lane >> 4;
  int m0 = blockIdx.y * 128, n0 = blockIdx.x * 64;
  int mh = (w & 1) * 64, nh = (w >> 1) * 32;
  f32x4 acc[4][2];
  #pragma unroll
  for (int i = 0; i < 4; i++)
    #pragma unroll
    for (int j = 0; j < 2; j++) acc[i][j] = f32x4{0.f, 0.f, 0.f, 0.f};

  int srow = lane >> 3, sc = lane & 7;

  for (int k0 = 0; k0 < K; k0 += 64) {
    __syncthreads();
    #pragma unroll
    for (int i = 0; i < 4; i++) {
      int R0 = w * 32 + i * 8;
      int row = R0 + srow;
      int cg = sc ^ (row & 7);
      gload_lds16(A + (size_t)(m0 + row) * K + k0 + cg * 8, &As[R0 * 64]);
    }
    #pragma unroll
    for (int i = 0; i < 2; i++) {
      int R0 = w * 16 + i * 8;
      int row = R0 + srow;
      int cg = sc ^ (row & 7);
      gload_lds16(Bt + (size_t)(n0 + row) * K + k0 + cg * 8, &Bs[R0 * 64]);
    }
    __syncthreads();
    #pragma unroll
    for (int kk = 0; kk < 2; kk++) {
      half8 af[4], bf[2];
      #pragma unroll
      for (int t = 0; t < 4; t++) {
        int rr = mh + t * 16 + cc;
        af[t] = *(const half8*)&As[rr * 64 + (((kk * 4 + qq) ^ (rr & 7)) << 3)];
      }
      #pragma unroll
      for (int t = 0; t < 2; t++) {
        int rr = nh + t * 16 + cc;
        bf[t] = *(const half8*)&Bs[rr * 64 + (((kk * 4 + qq) ^ (rr & 7)) << 3)];
      }
      #pragma unroll
      for (int ti = 0; ti < 4; ti++)
        #pragma unroll
        for (int tj = 0; tj < 2; tj++)
          acc[ti][tj] = MFMA16(af[ti], bf[tj], acc[ti][tj]);
    }
  }

  float aSv[2], aDv[2];
  #pragma unroll
  for (int tj = 0; tj < 2; tj++) {
    int colg = n0 + nh + tj * 16 + cc;
    aSv[tj] = aS[colg];
    aDv[tj] = aD[colg];
  }
  #pragma unroll
  for (int ti = 0; ti < 4; ti++) {
    #pragma unroll
    for (int i = 0; i < 4; i++) {
      int rloc = mh + ti * 16 + qq * 4 + i;      // 0..127
      float ps = 0.f, pd = 0.f;
      #pragma unroll
      for (int tj = 0; tj < 2; tj++) {
        int colg = n0 + nh + tj * 16 + cc;
        float v = acc[ti][tj][i];
        if (FP8O) {
          int pk = __builtin_amdgcn_cvt_pk_fp8_f32(v, v, 0, false);
          out8[(size_t)(m0 + rloc) * NC + colg] = (unsigned char)pk;
        } else {
          outh[(size_t)(m0 + rloc) * NC + colg] = (half_t)v;
        }
        ps += v * aSv[tj];
        pd += v * aDv[tj];
      }
      #pragma unroll
      for (int off = 1; off < 16; off <<= 1) {
        ps += __shfl_xor(ps, off);
        pd += __shfl_xor(pd, off);
      }
      if (cc == 0) {
        sRed[0][w][ti * 16 + qq * 4 + i] = ps;
        sRed[1][w][ti * 16 + qq * 4 + i] = pd;
      }
    }
  }
  __syncthreads();
  if (threadIdx.x < 128) {
    int row = threadIdx.x;
    int wlo = row >> 6, ri = row & 63;
    float ps = sRed[0][wlo][ri] + sRed[0][wlo + 2][ri];
    float pd = sRed[1][wlo][ri] + sRed[1][wlo + 2][ri];
    if (H == 4) {
      int head = n0 >> 6;
      es[(size_t)(m0 + row) * 4 + head] = ps;
      ed[(size_t)(m0 + row) * 4 + head] = pd;
    } else {
      atomicAdd(&es[m0 + row], ps);
      atomicAdd(&ed[m0 + row], pd);
    }
  }
}

// ---------------- fused Wo-GEMM + residual + LayerNorm (+ es/ed zeroing) ----------------
__global__ __launch_bounds__(256) void k_gemm_ln(
    const half_t* __restrict__ A, const half_t* __restrict__ Bt,
    const float* __restrict__ bias, const half_t* __restrict__ res,
    const float* __restrict__ gamma, const float* __restrict__ beta,
    half_t* __restrict__ outh, float* __restrict__ es0, float* __restrict__ ed0)
{
  __shared__ __align__(16) half_t As[64 * 64];
  __shared__ __align__(16) half_t Bs[256 * 64];
  __shared__ float sSum[4][64], sSq[4][64];
  __shared__ float sMR[64][2];
  int w = threadIdx.x >> 6, lane = threadIdx.x & 63;
  int r = lane & 15, q = lane >> 4;
  int m0 = blockIdx.x * 64;
  int nh = w * 64;

  if (threadIdx.x < 64) es0[m0 + threadIdx.x] = 0.f;
  else if (threadIdx.x < 128) ed0[m0 + threadIdx.x - 64] = 0.f;

  f32x4 acc[4][4];
  #pragma unroll
  for (int i = 0; i < 4; i++)
    #pragma unroll
    for (int j = 0; j < 4; j++) acc[i][j] = f32x4{0.f, 0.f, 0.f, 0.f};

  int srow = lane >> 3, sc = lane & 7;

  for (int k0 = 0; k0 < 256; k0 += 64) {
    __syncthreads();
    #pragma unroll
    for (int i = 0; i < 2; i++) {
      int R0 = w * 16 + i * 8;
      int row = R0 + srow;
      int cg = sc ^ (row & 7);
      gload_lds16(A + (size_t)(m0 + row) * 256 + k0 + cg * 8, &As[R0 * 64]);
    }
    #pragma unroll
    for (int i = 0; i < 8; i++) {
      int R0 = w * 64 + i * 8;
      int row = R0 + srow;
      int cg = sc ^ (row & 7);
      gload_lds16(Bt + (size_t)row * 256 + k0 + cg * 8, &Bs[R0 * 64]);
    }
    __syncthreads();
    #pragma unroll
    for (int kk = 0; kk < 2; kk++) {
      half8 af[4], bf[4];
      #pragma unroll
      for (int t = 0; t < 4; t++) {
        int rr = t * 16 + r;
        af[t] = *(const half8*)&As[rr * 64 + (((kk * 4 + q) ^ (rr & 7)) << 3)];
      }
      #pragma unroll
      for (int t = 0; t < 4; t++) {
        int rr = nh + t * 16 + r;
        bf[t] = *(const half8*)&Bs[rr * 64 + (((kk * 4 + q) ^ (rr & 7)) << 3)];
      }
      #pragma unroll
      for (int ti = 0; ti < 4; ti++)
        #pragma unroll
        for (int tj = 0; tj < 4; tj++)
          acc[ti][tj] = MFMA16(af[ti], bf[tj], acc[ti][tj]);
    }
  }

  float gv[4], bv[4];
  #pragma unroll
  for (int tj = 0; tj < 4; tj++) {
    int col = nh + tj * 16 + r;
    gv[tj] = gamma[col];
    bv[tj] = beta[col];
  }
  #pragma unroll
  for (int ti = 0; ti < 4; ti++) {
    #pragma unroll
    for (int i = 0; i < 4; i++) {
      int row = ti * 16 + q * 4 + i;
      float s = 0.f, ss = 0.f;
      #pragma unroll
      for (int tj = 0; tj < 4; tj++) {
        int col = nh + tj * 16 + r;
        float v = acc[ti][tj][i] + bias[col]
                + (float)res[(size_t)(m0 + row) * 256 + col];
        acc[ti][tj][i] = v;
        s += v;
        ss += v * v;
      }
      #pragma unroll
      for (int off = 1; off < 16; off <<= 1) {
        s  += __shfl_xor(s, off);
        ss += __shfl_xor(ss, off);
      }
      if (r == 0) { sSum[w][row] = s; sSq[w][row] = ss; }
    }
  }
  __syncthreads();
  if (threadIdx.x < 64) {
    int row = threadIdx.x;
    float s  = sSum[0][row] + sSum[1][row] + sSum[2][row] + sSum[3][row];
    float ss = sSq[0][row] + sSq[1][row] + sSq[2][row] + sSq[3][row];
    float mean = s * (1.f / 256.f);
    float var  = ss * (1.f / 256.f) - mean * mean;
    sMR[row][0] = mean;
    sMR[row][1] = rsqrtf(var + 1e-5f);
  }
  __syncthreads();
  #pragma unroll
  for (int ti = 0; ti < 4; ti++) {
    #pragma unroll
    for (int i = 0; i < 4; i++) {
      int row = ti * 16 + q * 4 + i;
      float mean = sMR[row][0], rstd = sMR[row][1];
      #pragma unroll
      for (int tj = 0; tj < 4; tj++) {
        int col = nh + tj * 16 + r;
        outh[(size_t)(m0 + row) * 256 + col] =
            (half_t)((acc[ti][tj][i] - mean) * rstd * gv[tj] + bv[tj]);
      }
    }
  }
}

// ---------------- fp16-gather aggregation (HC=256, H=4, fp16 acc, ELU) ----------------
__global__ __launch_bounds__(256) void k_agg_f16(
    const half_t* __restrict__ h, const float* __restrict__ es,
    const float* __restrict__ ed, const float* __restrict__ bias,
    const int* __restrict__ rowptr, const int* __restrict__ col,
    half_t* __restrict__ outh)
{
  int lane = threadIdx.x & 63;
  int g = lane >> 4, li = lane & 15;
  int n = blockIdx.x * 4 + (threadIdx.x >> 6);
  int cbase = li * 16;
  int hl = li >> 2;
  float edn = ed[(size_t)n * 4 + hl];
  int j0 = rowptr[n], j1 = rowptr[n + 1];
  const half_t* hb = h + cbase;

  float sum0 = 0.f, sum1 = 0.f;
  half8 acc0[2], acc1[2];
  #pragma unroll
  for (int i = 0; i < 2; i++) {
    acc0[i] = half8{0, 0, 0, 0, 0, 0, 0, 0};
    acc1[i] = half8{0, 0, 0, 0, 0, 0, 0, 0};
  }
  for (int j = j0 + g; j < j1; j += 8) {
    int jb = j + 4;
    int s0 = col[j];
    int s1 = col[(jb < j1) ? jb : j];
    float e0 = es[(size_t)s0 * 4 + hl] + edn;
    e0 = fmaxf(e0, 0.2f * e0);
    float e1 = es[(size_t)s1 * 4 + hl] + edn;
    e1 = fmaxf(e1, 0.2f * e1);
    e1 = (jb < j1) ? e1 : -1e30f;
    const half_t* hp0 = hb + (size_t)s0 * 256;
    const half_t* hp1 = hb + (size_t)s1 * 256;
    float p0 = exp2f(e0 * 1.44269504f - 8.65617025f);
    float p1 = exp2f(e1 * 1.44269504f - 8.65617025f);
    sum0 += p0; sum1 += p1;
    half_t q0 = (half_t)p0, q1 = (half_t)p1;
    half8 pv0 = {q0, q0, q0, q0, q0, q0, q0, q0};
    half8 pv1 = {q1, q1, q1, q1, q1, q1, q1, q1};
    #pragma unroll
    for (int i = 0; i < 2; i++) {
      half8 v0 = *(const half8*)(hp0 + i * 8);
      half8 v1 = *(const half8*)(hp1 + i * 8);
      acc0[i] += pv0 * v0;
      acc1[i] += pv1 * v1;
    }
  }
  float sum = sum0 + sum1;
  sum += __shfl_xor(sum, 16);
  sum += __shfl_xor(sum, 32);
  float av[16];
  #pragma unroll
  for (int i = 0; i < 16; i++) {
    av[i] = (float)acc0[i >> 3][i & 7] + (float)acc1[i >> 3][i & 7];
    av[i] += __shfl_xor(av[i], 16);
    av[i] += __shfl_xor(av[i], 32);
  }
  float inv = 1.f / sum;
  if (g == 0) {
    size_t obase = (size_t)n * 256 + cbase;
    #pragma unroll
    for (int p8 = 0; p8 < 2; p8++) {
      half8 hv;
      #pragma unroll
      for (int i = 0; i < 8; i++) {
        float t = av[p8 * 8 + i] * inv + bias[cbase + p8 * 8 + i];
        t = (t > 0.f) ? t : __expf(t) - 1.f;     // jax.nn.elu
        hv[i] = (half_t)t;
      }
      *(half8*)(outh + obase + p8 * 8) = hv;
    }
  }
}

// ---------------- fp8-gather aggregation (HC=256, H=4, ELU) ----------------
__global__ __launch_bounds__(256) void k_agg_fp8(
    const unsigned char* __restrict__ hq, const float* __restrict__ es,
    const float* __restrict__ ed, const float* __restrict__ bias,
    const int* __restrict__ rowptr, const int* __restrict__ col,
    half_t* __restrict__ outh)
{
  int lane = threadIdx.x & 63;
  int g = lane >> 4, li = lane & 15;
  int n = blockIdx.x * 4 + (threadIdx.x >> 6);
  int cbase = li * 16;
  int hl = li >> 2;
  float edn = ed[(size_t)n * 4 + hl];
  int j0 = rowptr[n], j1 = rowptr[n + 1];
  const unsigned char* hb = hq + cbase;

  float sum0 = 0.f, sum1 = 0.f;
  half2v a0[8], a1[8];
  #pragma unroll
  for (int i = 0; i < 8; i++) { a0[i] = half2v{0, 0}; a1[i] = half2v{0, 0}; }

  for (int j = j0 + g; j < j1; j += 8) {
    int jb = j + 4;
    int s0 = col[j];
    int s1 = col[(jb < j1) ? jb : j];
    float e0 = es[(size_t)s0 * 4 + hl] + edn;
    e0 = fmaxf(e0, 0.2f * e0);
    float e1 = es[(size_t)s1 * 4 + hl] + edn;
    e1 = fmaxf(e1, 0.2f * e1);
    e1 = (jb < j1) ? e1 : -1e30f;
    int4 d0 = *(const int4*)(hb + (size_t)s0 * 256);
    int4 d1 = *(const int4*)(hb + (size_t)s1 * 256);
    float p0 = exp2f(e0 * 1.44269504f - 8.65617025f);
    float p1 = exp2f(e1 * 1.44269504f - 8.65617025f);
    sum0 += p0; sum1 += p1;
    half_t q0 = (half_t)p0, q1 = (half_t)p1;
    half2v pv0 = {q0, q0}, pv1 = {q1, q1};
    fp8x4_fma(d0.x, pv0, &a0[0]); fp8x4_fma(d0.y, pv0, &a0[2]);
    fp8x4_fma(d0.z, pv0, &a0[4]); fp8x4_fma(d0.w, pv0, &a0[6]);
    fp8x4_fma(d1.x, pv1, &a1[0]); fp8x4_fma(d1.y, pv1, &a1[2]);
    fp8x4_fma(d1.z, pv1, &a1[4]); fp8x4_fma(d1.w, pv1, &a1[6]);
  }

  float sum = sum0 + sum1;
  sum += __shfl_xor(sum, 16);
  sum += __shfl_xor(sum, 32);
  float av[16];
  #pragma unroll
  for (int i = 0; i < 16; i++) {
    av[i] = (float)a0[i >> 1][i & 1] + (float)a1[i >> 1][i & 1];
    av[i] += __shfl_xor(av[i], 16);
    av[i] += __shfl_xor(av[i], 32);
  }
  float inv = 1.f / sum;
  if (g == 0) {
    size_t obase = (size_t)n * 256 + cbase;
    #pragma unroll
    for (int p8 = 0; p8 < 2; p8++) {
      half8 hv;
      #pragma unroll
      for (int i = 0; i < 8; i++) {
        float t = av[p8 * 8 + i] * inv + bias[cbase + p8 * 8 + i];
        t = (t > 0.f) ? t : __expf(t) - 1.f;
        hv[i] = (half_t)t;
      }
      *(half8*)(outh + obase + p8 * 8) = hv;
    }
  }
}

// ---------------- fp16-gather aggregation (GAT3: HC=128, H=1, fp32 acc) ----------------
__global__ __launch_bounds__(256) void k_agg3(
    const half_t* __restrict__ h, const float* __restrict__ es,
    const float* __restrict__ ed, const float* __restrict__ bias,
    const int* __restrict__ rowptr, const int* __restrict__ col,
    float* __restrict__ outf)
{
  constexpr int VPT = 8;
  int lane = threadIdx.x & 63;
  int g = lane >> 4, li = lane & 15;
  int n = blockIdx.x * 4 + (threadIdx.x >> 6);
  int cbase = li * VPT;
  float edn = ed[n];
  int j0 = rowptr[n], j1 = rowptr[n + 1];
  const half_t* hb = h + cbase;

  float sum0 = 0.f, sum1 = 0.f;
  float acc0[VPT], acc1[VPT];
  #pragma unroll
  for (int i = 0; i < VPT; i++) { acc0[i] = 0.f; acc1[i] = 0.f; }
  for (int j = j0 + g; j < j1; j += 8) {
    int jb = j + 4;
    int s0 = col[j];
    int s1 = col[(jb < j1) ? jb : j];
    float e0 = es[s0] + edn;
    e0 = fmaxf(e0, 0.2f * e0);
    float e1 = es[s1] + edn;
    e1 = fmaxf(e1, 0.2f * e1);
    e1 = (jb < j1) ? e1 : -1e30f;
    const half_t* hp0 = hb + (size_t)s0 * 128;
    const half_t* hp1 = hb + (size_t)s1 * 128;
    float p0 = __expf(e0), p1 = __expf(e1);
    sum0 += p0; sum1 += p1;
    half8 v0 = *(const half8*)hp0;
    half8 v1 = *(const half8*)hp1;
    #pragma unroll
    for (int i = 0; i < 8; i++) {
      acc0[i] += p0 * (float)v0[i];
      acc1[i] += p1 * (float)v1[i];
    }
  }
  float sum = sum0 + sum1;
  sum += __shfl_xor(sum, 16);
  sum += __shfl_xor(sum, 32);
  float av[VPT];
  #pragma unroll
  for (int i = 0; i < VPT; i++) {
    av[i] = acc0[i] + acc1[i];
    av[i] += __shfl_xor(av[i], 16);
    av[i] += __shfl_xor(av[i], 32);
  }
  float inv = 1.f / sum;
  if (g == 0) {
    size_t obase = (size_t)n * 128 + cbase;
    #pragma unroll
    for (int p4 = 0; p4 < 2; p4++) {
      float4 fv = {av[p4 * 4] * inv + bias[cbase + p4 * 4],
                   av[p4 * 4 + 1] * inv + bias[cbase + p4 * 4 + 1],
                   av[p4 * 4 + 2] * inv + bias[cbase + p4 * 4 + 2],
                   av[p4 * 4 + 3] * inv + bias[cbase + p4 * 4 + 3]};
      *(float4*)(outf + obase + p4 * 4) = fv;
    }
  }
}

// ---------------- MHA core (R0 known-good: 64-key tiles, 25 KB LDS) ----------------
__global__ __launch_bounds__(256) void k_attn(
    const half_t* __restrict__ qk, const half_t* __restrict__ vt,
    half_t* __restrict__ o)
{
  __shared__ __align__(16) half_t Kt[64 * 64];
  __shared__ __align__(16) half_t Vt[64 * 64];
  __shared__ __align__(16) half_t Pb[4][16][72];

  int pair = blockIdx.x;
  int b = pair >> 2, hh = pair & 3;
  int q0 = blockIdx.y * 64;
  int w = threadIdx.x >> 6, lane = threadIdx.x & 63;
  int cc = lane & 15, qq = lane >> 4;

  const half_t* Qp = qk + ((size_t)(b * NPG_ + q0 + w * 16 + cc) * 512 + hh * 64);
  half8 qa0 = *(const half8*)(Qp + qq * 8);
  half8 qa1 = *(const half8*)(Qp + 32 + qq * 8);

  f32x4 oacc[4];
  #pragma unroll
  for (int t = 0; t < 4; t++) oacc[t] = f32x4{0.f, 0.f, 0.f, 0.f};
  float rs = 0.f;

  const half_t* kb = qk + ((size_t)(b * NPG_) * 512 + 256 + hh * 64);
  const half_t* vb = vt + ((size_t)(hh * 64) * 32768 + b * NPG_);

  int krow = lane >> 3, ksl = lane & 7;

  for (int kt = 0; kt < 8; kt++) {
    __syncthreads();
    #pragma unroll
    for (int i = 0; i < 2; i++) {
      int R = w * 16 + i * 8;
      int kr = R + krow;
      gload_lds16(kb + (size_t)(kt * 64 + kr) * 512 + ((ksl ^ (kr & 7)) * 8),
                  &Kt[R * 64]);
      gload_lds16(vb + (size_t)kr * 32768 + kt * 64 + ((ksl ^ (kr & 7)) * 8),
                  &Vt[R * 64]);
    }
    __syncthreads();

    #pragma unroll
    for (int mt = 0; mt < 4; mt++) {
      int key = mt * 16 + cc;
      half8 k0 = *(const half8*)&Kt[key * 64 + ((qq ^ (key & 7)) << 3)];
      half8 k1 = *(const half8*)&Kt[key * 64 + (((qq + 4) ^ (key & 7)) << 3)];
      f32x4 s = f32x4{0.f, 0.f, 0.f, 0.f};
      s = MFMA16(k0, qa0, s);
      s = MFMA16(k1, qa1, s);
      half4v ph;
      #pragma unroll
      for (int i = 0; i < 4; i++) {
        float p = exp2f(s[i] * 0.180336886f - 11.54156033f);
        rs += p;
        ph[i] = (half_t)p;
      }
      *(half4v*)&Pb[w][cc][mt * 16 + qq * 4] = ph;
    }

    #pragma unroll
    for (int kc = 0; kc < 2; kc++) {
      half8 a = *(const half8*)&Pb[w][cc][kc * 32 + qq * 8];
      #pragma unroll
      for (int nt = 0; nt < 4; nt++) {
        int d = nt * 16 + cc;
        half8 bb = *(const half8*)&Vt[d * 64 + (((kc * 4 + qq) ^ (d & 7)) << 3)];
        oacc[nt] = MFMA16(a, bb, oacc[nt]);
      }
    }
  }

  rs += __shfl_xor(rs, 16);
  rs += __shfl_xor(rs, 32);
  #pragma unroll
  for (int i = 0; i < 4; i++) {
    float rsv = __shfl(rs, qq * 4 + i);
    float inv = 1.f / rsv;
    int node = b * NPG_ + q0 + w * 16 + qq * 4 + i;
    #pragma unroll
    for (int nt = 0; nt < 4; nt++)
      o[(size_t)node * 256 + hh * 64 + nt * 16 + cc] = (half_t)(oacc[nt][i] * inv);
  }
}

// ---------------- host ----------------
extern "C" void kernel_launch(void* const* d_in, const int* in_sizes, int n_in,
                              void* d_out, int out_size, void* d_ws, size_t ws_size,
                              hipStream_t stream)
{
  const float* x    = (const float*)d_in[0];
  const int*   ei   = (const int*)d_in[1];
  const float* W1   = (const float*)d_in[3];
  const float* aS1  = (const float*)d_in[4];
  const float* aD1  = (const float*)d_in[5];
  const float* b1   = (const float*)d_in[6];
  const float* W2   = (const float*)d_in[7];
  const float* aS2  = (const float*)d_in[8];
  const float* aD2  = (const float*)d_in[9];
  const float* b2   = (const float*)d_in[10];
  const float* W3   = (const float*)d_in[11];
  const float* aS3  = (const float*)d_in[12];
  const float* aD3  = (const float*)d_in[13];
  const float* b3   = (const float*)d_in[14];
  const float* Wi   = (const float*)d_in[15];
  const float* bi   = (const float*)d_in[16];
  const float* Wo   = (const float*)d_in[17];
  const float* bo   = (const float*)d_in[18];
  const float* gam  = (const float*)d_in[19];
  const float* bet  = (const float*)d_in[20];
  float* out = (float*)d_out;
  const int N = N_NODES;
  int E = in_sizes[1] / 2;

  char* ws = (char*)d_ws;
  size_t off = 0;
  auto alloc = [&](size_t bytes) -> void* {
    void* p = ws + off;
    off = (off + bytes + 255) & ~(size_t)255;
    return p;
  };
  half_t* x_h    = (half_t*)alloc((size_t)N * 128 * 2);
  half_t* h_h    = (half_t*)alloc((size_t)N * 256 * 2);   // h1 / h3 (fp16)
  unsigned char* hq = (unsigned char*)alloc((size_t)N * 256);  // h2 (fp8)
  half_t* x1_h   = (half_t*)alloc((size_t)N * 256 * 2);
  half_t* x2_h   = (half_t*)alloc((size_t)N * 256 * 2);
  half_t* qk_h   = (half_t*)alloc((size_t)N * 512 * 2);
  half_t* vt_h   = (half_t*)alloc((size_t)256 * N * 2);   // V^T: [256][32768]
  half_t* o_h    = (half_t*)alloc((size_t)N * 256 * 2);
  half_t* x2a_h  = (half_t*)alloc((size_t)N * 256 * 2);
  half_t* W1t    = (half_t*)alloc(256 * 128 * 2);
  half_t* W2t    = (half_t*)alloc(256 * 256 * 2);
  half_t* W3t    = (half_t*)alloc(128 * 256 * 2);
  half_t* Wi_h   = (half_t*)alloc(768 * 256 * 2);
  half_t* Wo_h   = (half_t*)alloc(256 * 256 * 2);
  float*  es     = (float*) alloc((size_t)N * 4 * 4);
  float*  ed     = (float*) alloc((size_t)N * 4 * 4);
  int*    deg    = (int*)   alloc((size_t)N * 4);
  int*    rank   = (int*)   alloc((size_t)E * 4);
  int*    rowptr = (int*)   alloc(((size_t)N + 1) * 4);
  int*    col    = (int*)   alloc((size_t)(N + E) * 4);

  const int* srcE = ei;
  const int* dstE = ei + E;

  // R7/R9: deg zeroed on-stream; histogram+rank folded into k_convert tail
  hipMemsetAsync(deg, 0, (size_t)N * 4, stream);
  int convGrid = 4864 + (E + 255) / 256;
  k_convert<<<convGrid, 256, 0, stream>>>(x, x_h, W1, W1t, W2, W2t, W3, W3t,
                                          Wi, Wi_h, Wo, Wo_h, dstE, deg, rank, E);
  // R10: single-kernel two-level scan (replaces scan1 + scan23)
  k_scan_all<<<128, 256, 0, stream>>>(deg, rowptr, col);

  // ---- GAT1 GEMM + fused atomic-free edge scatter (R9) ----
  int eyr = (E + 1023) / 1024;
  k_gemm_gat<256, 4, false, true><<<dim3(4, N / 128 + eyr), 256, 0, stream>>>(
      x_h, W1t, h_h, nullptr, 128, aS1, aD1, es, ed,
      srcE, dstE, rowptr, rank, col, E);
  k_agg_f16<<<N / 4, 256, 0, stream>>>(h_h, es, ed, b1, rowptr, col, x1_h);

  // ---- GAT2 (fp8 gather path): h2 (fp8) + es/ed ; fp8 aggregate -> x2 ----
  k_gemm_gat<256, 4, true, false><<<dim3(4, N / 128), 256, 0, stream>>>(
      x1_h, W2t, nullptr, hq, 256, aS2, aD2, es, ed,
      nullptr, nullptr, nullptr, nullptr, nullptr, 0);
  k_agg_fp8<<<N / 4, 256, 0, stream>>>(hq, es, ed, b2, rowptr, col, x2_h);

  // ---- MHA: merged QK + V^T projections (independent -> one launch) ----
  k_gemm_qkv2<<<3072, 256, 0, stream>>>(x2_h, Wi_h, bi, qk_h, vt_h);
  k_attn<<<dim3(256, 8), 256, 0, stream>>>(qk_h, vt_h, o_h);

  // ---- Wo-GEMM + residual + LayerNorm fused -> x2a; also zeroes es/ed ----
  k_gemm_ln<<<N / 64, 256, 0, stream>>>(o_h, Wo_h, bo, x2_h, gam, bet, x2a_h, es, ed);

  // ---- GAT3 (H=1, C=128, fp16 h, fp32 acc; atomic es/ed partials) -> d_out ----
  k_gemm_gat<128, 1, false, false><<<dim3(2, N / 128), 256, 0, stream>>>(
      x2a_h, W3t, h_h, nullptr, 256, aS3, aD3, es, ed,
      nullptr, nullptr, nullptr, nullptr, nullptr, 0);
  k_agg3<<<N / 4, 256, 0, stream>>>(h_h, es, ed, b3, rowptr, col, out);
}

// Round 12
// 367.920 us; speedup vs baseline: 1.0308x; 1.0308x over previous
//
#include <hip/hip_runtime.h>

typedef _Float16 half_t;
typedef _Float16 half8  __attribute__((ext_vector_type(8)));
typedef _Float16 half4v __attribute__((ext_vector_type(4)));
typedef _Float16 half2v __attribute__((ext_vector_type(2)));
typedef float    f32x4  __attribute__((ext_vector_type(4)));
typedef float    f32x2  __attribute__((ext_vector_type(2)));

constexpr int N_NODES = 32768;
constexpr int NPG_    = 512;

#define MFMA16(a, b, c) __builtin_amdgcn_mfma_f32_16x16x32_f16((a), (b), (c), 0, 0, 0)

#if defined(__has_builtin)
#  if __has_builtin(__builtin_amdgcn_cvt_pk_f16_fp8)
#    define HAVE_PK_F16_FP8 1
#  else
#    define HAVE_PK_F16_FP8 0
#  endif
#else
#  define HAVE_PK_F16_FP8 0
#endif

__device__ __forceinline__ void gload_lds16(const half_t* g, half_t* l) {
  __builtin_amdgcn_global_load_lds(
      (const __attribute__((address_space(1))) void*)g,
      (__attribute__((address_space(3))) void*)l, 16, 0, 0);
}

// decode 4 fp8 (one dword) and fma into 2 half2 accumulators with weight p
__device__ __forceinline__ void fp8x4_fma(int wrd, half2v p, half2v* acc) {
#if HAVE_PK_F16_FP8
  half2v lo = __builtin_amdgcn_cvt_pk_f16_fp8((short)(wrd & 0xffff));
  half2v hi = __builtin_amdgcn_cvt_pk_f16_fp8((short)(((unsigned)wrd) >> 16));
#else
  f32x2 flo = __builtin_amdgcn_cvt_pk_f32_fp8(wrd, false);
  f32x2 fhi = __builtin_amdgcn_cvt_pk_f32_fp8(wrd, true);
  half2v lo = {(half_t)flo.x, (half_t)flo.y};
  half2v hi = {(half_t)fhi.x, (half_t)fhi.y};
#endif
  acc[0] += p * lo;
  acc[1] += p * hi;
}

// ---------------- CSR build ----------------
// R7: histogram folded into k_convert tail; k_scan1 reads deg[i]+1 (self-loop).
// R8: scan2 folded into scan3; scatter folded into GAT1 GEMM launch.
// R9: scatter atomics ELIMINATED via per-edge rank (histogram atomic's return).
// R11: R10's single-kernel scan reverted (redundant 16MB deg re-read cost more
//      than the launch it saved).
__global__ __launch_bounds__(256) void k_scan1(const int* __restrict__ deg,
                                               int* __restrict__ partial,
                                               int* __restrict__ blockSums) {
  __shared__ int sd[256];
  int t = threadIdx.x;
  int i = blockIdx.x * 256 + t;
  int v = deg[i] + 1;          // +1 = self-loop (deg holds in-edges only)
  sd[t] = v;
  __syncthreads();
  int acc = v;
  for (int off = 1; off < 256; off <<= 1) {
    int add = (t >= off) ? sd[t - off] : 0;
    __syncthreads();
    acc += add;
    sd[t] = acc;
    __syncthreads();
  }
  partial[i] = acc - v;
  if (t == 255) blockSums[blockIdx.x] = acc;
}

// scan2+scan3 fused: every block redundantly scans blockSums (128 ints) in LDS,
// then applies its own exclusive offset. Self-loop goes to slot rowptr[i].
__global__ __launch_bounds__(256) void k_scan23(
    const int* __restrict__ partial, const int* __restrict__ blockSums,
    int* __restrict__ rowptr, int* __restrict__ col)
{
  __shared__ int sd[128];
  int t = threadIdx.x;
  if (t < 128) sd[t] = blockSums[t];
  __syncthreads();
  for (int off = 1; off < 128; off <<= 1) {
    int add = (t < 128 && t >= off) ? sd[t - off] : 0;
    __syncthreads();
    if (t < 128) sd[t] += add;
    __syncthreads();
  }
  int bo = (blockIdx.x == 0) ? 0 : sd[blockIdx.x - 1];
  int i = blockIdx.x * 256 + t;
  int rp = partial[i] + bo;
  rowptr[i] = rp;
  col[rp] = i;
  if (blockIdx.x == 127 && t == 255) rowptr[N_NODES] = sd[127];
}

// ---------------- fused conversions + edge histogram + rank (R9) ----------------
__global__ void k_convert(
    const float* __restrict__ x,  half_t* __restrict__ x_h,
    const float* __restrict__ W1, half_t* __restrict__ W1t,
    const float* __restrict__ W2, half_t* __restrict__ W2t,
    const float* __restrict__ W3, half_t* __restrict__ W3t,
    const float* __restrict__ Wi, half_t* __restrict__ Wi_h,
    const float* __restrict__ Wo, half_t* __restrict__ Wo_h,
    const int* __restrict__ dst, int* __restrict__ deg,
    int* __restrict__ rank, int E)
{
  int bid = blockIdx.x, t = threadIdx.x;
  if (bid < 4096) {
    int i = bid * 256 + t;
    float4 v = *(const float4*)(x + (size_t)i * 4);
    half4v h = {(half_t)v.x, (half_t)v.y, (half_t)v.z, (half_t)v.w};
    *(half4v*)(x_h + (size_t)i * 4) = h;
  } else if (bid < 4224) {
    int i = (bid - 4096) * 256 + t;
    int o = i >> 7, k = i & 127;
    W1t[i] = (half_t)W1[k * 256 + o];
  } else if (bid < 4480) {
    int i = (bid - 4224) * 256 + t;
    int o = i >> 8, k = i & 255;
    W2t[i] = (half_t)W2[k * 256 + o];
  } else if (bid < 4608) {
    int i = (bid - 4480) * 256 + t;
    int o = i >> 8, k = i & 255;
    W3t[i] = (half_t)W3[k * 128 + o];
  } else if (bid < 4800) {
    int i = (bid - 4608) * 256 + t;
    float4 v = *(const float4*)(Wi + (size_t)i * 4);
    half4v h = {(half_t)v.x, (half_t)v.y, (half_t)v.z, (half_t)v.w};
    *(half4v*)(Wi_h + (size_t)i * 4) = h;
  } else if (bid < 4864) {
    int i = (bid - 4800) * 256 + t;
    float4 v = *(const float4*)(Wo + (size_t)i * 4);
    half4v h = {(half_t)v.x, (half_t)v.y, (half_t)v.z, (half_t)v.w};
    *(half4v*)(Wo_h + (size_t)i * 4) = h;
  } else {
    // edge histogram; atomic return value = this edge's rank in its segment
    int i = (bid - 4864) * 256 + t;
    if (i < E) rank[i] = atomicAdd(&deg[dst[i]], 1);
  }
}

// ---------------- residency-first GEMM body (tile 128x64, BK=64) ----------------
__device__ __forceinline__ void gemm_wide_body(
    int bx, int by,
    const half_t* __restrict__ A, const half_t* __restrict__ Bt,
    const float* __restrict__ bias, int bias_per_row,
    half_t* __restrict__ outh, int Nc, int K,
    half_t* As, half_t* Bs)
{
  int w = threadIdx.x >> 6, lane = threadIdx.x & 63;
  int r = lane & 15, q = lane >> 4;
  int m0 = by * 128, n0 = bx * 64;
  int mh = (w & 1) * 64, nh = (w >> 1) * 32;
  f32x4 acc[4][2];
  #pragma unroll
  for (int i = 0; i < 4; i++)
    #pragma unroll
    for (int j = 0; j < 2; j++) acc[i][j] = f32x4{0.f, 0.f, 0.f, 0.f};

  int srow = lane >> 3, sc = lane & 7;

  for (int k0 = 0; k0 < K; k0 += 64) {
    __syncthreads();
    #pragma unroll
    for (int i = 0; i < 4; i++) {
      int R0 = w * 32 + i * 8;
      int row = R0 + srow;
      int cg = sc ^ (row & 7);
      gload_lds16(A + (size_t)(m0 + row) * K + k0 + cg * 8, &As[R0 * 64]);
    }
    #pragma unroll
    for (int i = 0; i < 2; i++) {
      int R0 = w * 16 + i * 8;
      int row = R0 + srow;
      int cg = sc ^ (row & 7);
      gload_lds16(Bt + (size_t)(n0 + row) * K + k0 + cg * 8, &Bs[R0 * 64]);
    }
    __syncthreads();
    #pragma unroll
    for (int kk = 0; kk < 2; kk++) {
      half8 af[4], bf[2];
      #pragma unroll
      for (int t = 0; t < 4; t++) {
        int rr = mh + t * 16 + r;
        af[t] = *(const half8*)&As[rr * 64 + (((kk * 4 + q) ^ (rr & 7)) << 3)];
      }
      #pragma unroll
      for (int t = 0; t < 2; t++) {
        int rr = nh + t * 16 + r;
        bf[t] = *(const half8*)&Bs[rr * 64 + (((kk * 4 + q) ^ (rr & 7)) << 3)];
      }
      #pragma unroll
      for (int ti = 0; ti < 4; ti++)
        #pragma unroll
        for (int tj = 0; tj < 2; tj++)
          acc[ti][tj] = MFMA16(af[ti], bf[tj], acc[ti][tj]);
    }
  }

  #pragma unroll
  for (int tj = 0; tj < 2; tj++) {
    int colc = n0 + nh + tj * 16 + r;
    float bc = bias_per_row ? 0.f : bias[colc];
    #pragma unroll
    for (int ti = 0; ti < 4; ti++) {
      #pragma unroll
      for (int i = 0; i < 4; i++) {
        int row = m0 + mh + ti * 16 + q * 4 + i;
        float bv = bias_per_row ? bias[row] : bc;
        outh[(size_t)row * Nc + colc] = (half_t)(acc[ti][tj][i] + bv);
      }
    }
  }
}

// merged QK-projection (2048 blocks) + V^T-projection (1024 blocks)
__global__ __launch_bounds__(256) void k_gemm_qkv2(
    const half_t* __restrict__ x2, const half_t* __restrict__ Wi_h,
    const float* __restrict__ bi,
    half_t* __restrict__ qk, half_t* __restrict__ vt)
{
  __shared__ __align__(16) half_t As[128 * 64];
  __shared__ __align__(16) half_t Bs[64 * 64];
  int id = blockIdx.x;
  if (id < 2048) {
    gemm_wide_body(id & 7, id >> 3, x2, Wi_h, bi, 0, qk, 512, 256, As, Bs);
  } else {
    int id2 = id - 2048;
    gemm_wide_body(id2 & 511, id2 >> 9, Wi_h + 512 * 256, x2, bi + 512, 1,
                   vt, 32768, 256, As, Bs);
  }
}

// ---------------- residency-first GAT GEMM: 128x64 tile + fused es/ed ----------------
// FUSE_SCAT (R9): extra blockIdx.y >= N/128 blocks perform the atomic-free
// rank-based edge scatter (independent of the GEMM; overlapped).
template<int NC, int H, bool FP8O, bool FUSE_SCAT>
__global__ __launch_bounds__(256) void k_gemm_gat(
    const half_t* __restrict__ A, const half_t* __restrict__ Bt,
    half_t* __restrict__ outh, unsigned char* __restrict__ out8, int K,
    const float* __restrict__ aS, const float* __restrict__ aD,
    float* __restrict__ es, float* __restrict__ ed,
    const int* __restrict__ srcE, const int* __restrict__ dstE,
    const int* __restrict__ rowptr, const int* __restrict__ rank,
    int* __restrict__ col, int E)
{
  __shared__ __align__(16) half_t As[128 * 64];
  __shared__ __align__(16) half_t Bs[64 * 64];
  __shared__ float sRed[2][4][64];

  if (FUSE_SCAT && (int)blockIdx.y >= N_NODES / 128) {
    int i = (((int)blockIdx.y - N_NODES / 128) * 4 + (int)blockIdx.x) * 256
            + (int)threadIdx.x;
    if (i < E) {
      int d = dstE[i];
      col[rowptr[d] + 1 + rank[i]] = srcE[i];   // +1: self-loop at slot 0
    }
    return;
  }

  int w = threadIdx.x >> 6, lane = threadIdx.x & 63;
  int cc = lane & 15, qq = lane >> 4;
  int m0 = blockIdx.y * 128, n0 = blockIdx.x * 64;
  int mh = (w & 1) * 64, nh = (w >> 1) * 32;
  f32x4 acc[4][2];
  #pragma unroll
  for (int i = 0; i < 4; i++)
    #pragma unroll
    for (int j = 0; j < 2; j++) acc[i][j] = f32x4{0.f, 0.f, 0.f, 0.f};

  int srow = lane >> 3, sc = lane & 7;

  for (int k0 = 0; k0 < K; k0 += 64) {
    __syncthreads();
    #pragma unroll
    for (int i = 0; i < 4; i++) {
      int R0 = w * 32 + i * 8;
      int row = R0 + srow;
      int cg = sc ^ (row & 7);
      gload_lds16(A + (size_t)(m0 + row) * K + k0 + cg * 8, &As[R0 * 64]);
    }
    #pragma unroll
    for (int i = 0; i < 2; i++) {
      int R0 = w * 16 + i * 8;
      int row = R0 + srow;
      int cg = sc ^ (row & 7);
      gload_lds16(Bt + (size_t)(n0 + row) * K + k0 + cg * 8, &Bs[R0 * 64]);
    }
    __syncthreads();
    #pragma unroll
    for (int kk = 0; kk < 2; kk++) {
      half8 af[4], bf[2];
      #pragma unroll
      for (int t = 0; t < 4; t++) {
        int rr = mh + t * 16 + cc;
        af[t] = *(const half8*)&As[rr * 64 + (((kk * 4 + qq) ^ (rr & 7)) << 3)];
      }
      #pragma unroll
      for (int t = 0; t < 2; t++) {
        int rr = nh + t * 16 + cc;
        bf[t] = *(const half8*)&Bs[rr * 64 + (((kk * 4 + qq) ^ (rr & 7)) << 3)];
      }
      #pragma unroll
      for (int ti = 0; ti < 4; ti++)
        #pragma unroll
        for (int tj = 0; tj < 2; tj++)
          acc[ti][tj] = MFMA16(af[ti], bf[tj], acc[ti][tj]);
    }
  }

  float aSv[2], aDv[2];
  #pragma unroll
  for (int tj = 0; tj < 2; tj++) {
    int colg = n0 + nh + tj * 16 + cc;
    aSv[tj] = aS[colg];
    aDv[tj] = aD[colg];
  }
  #pragma unroll
  for (int ti = 0; ti < 4; ti++) {
    #pragma unroll
    for (int i = 0; i < 4; i++) {
      int rloc = mh + ti * 16 + qq * 4 + i;      // 0..127
      float ps = 0.f, pd = 0.f;
      #pragma unroll
      for (int tj = 0; tj < 2; tj++) {
        int colg = n0 + nh + tj * 16 + cc;
        float v = acc[ti][tj][i];
        if (FP8O) {
          int pk = __builtin_amdgcn_cvt_pk_fp8_f32(v, v, 0, false);
          out8[(size_t)(m0 + rloc) * NC + colg] = (unsigned char)pk;
        } else {
          outh[(size_t)(m0 + rloc) * NC + colg] = (half_t)v;
        }
        ps += v * aSv[tj];
        pd += v * aDv[tj];
      }
      #pragma unroll
      for (int off = 1; off < 16; off <<= 1) {
        ps += __shfl_xor(ps, off);
        pd += __shfl_xor(pd, off);
      }
      if (cc == 0) {
        sRed[0][w][ti * 16 + qq * 4 + i] = ps;
        sRed[1][w][ti * 16 + qq * 4 + i] = pd;
      }
    }
  }
  __syncthreads();
  if (threadIdx.x < 128) {
    int row = threadIdx.x;
    int wlo = row >> 6, ri = row & 63;
    float ps = sRed[0][wlo][ri] + sRed[0][wlo + 2][ri];
    float pd = sRed[1][wlo][ri] + sRed[1][wlo + 2][ri];
    if (H == 4) {
      int head = n0 >> 6;
      es[(size_t)(m0 + row) * 4 + head] = ps;
      ed[(size_t)(m0 + row) * 4 + head] = pd;
    } else {
      atomicAdd(&es[m0 + row], ps);
      atomicAdd(&ed[m0 + row], pd);
    }
  }
}

// ---------------- fused Wo-GEMM + residual + LayerNorm (+ es/ed zeroing) ----------------
__global__ __launch_bounds__(256) void k_gemm_ln(
    const half_t* __restrict__ A, const half_t* __restrict__ Bt,
    const float* __restrict__ bias, const half_t* __restrict__ res,
    const float* __restrict__ gamma, const float* __restrict__ beta,
    half_t* __restrict__ outh, float* __restrict__ es0, float* __restrict__ ed0)
{
  __shared__ __align__(16) half_t As[64 * 64];
  __shared__ __align__(16) half_t Bs[256 * 64];
  __shared__ float sSum[4][64], sSq[4][64];
  __shared__ float sMR[64][2];
  int w = threadIdx.x >> 6, lane = threadIdx.x & 63;
  int r = lane & 15, q = lane >> 4;
  int m0 = blockIdx.x * 64;
  int nh = w * 64;

  if (threadIdx.x < 64) es0[m0 + threadIdx.x] = 0.f;
  else if (threadIdx.x < 128) ed0[m0 + threadIdx.x - 64] = 0.f;

  f32x4 acc[4][4];
  #pragma unroll
  for (int i = 0; i < 4; i++)
    #pragma unroll
    for (int j = 0; j < 4; j++) acc[i][j] = f32x4{0.f, 0.f, 0.f, 0.f};

  int srow = lane >> 3, sc = lane & 7;

  for (int k0 = 0; k0 < 256; k0 += 64) {
    __syncthreads();
    #pragma unroll
    for (int i = 0; i < 2; i++) {
      int R0 = w * 16 + i * 8;
      int row = R0 + srow;
      int cg = sc ^ (row & 7);
      gload_lds16(A + (size_t)(m0 + row) * 256 + k0 + cg * 8, &As[R0 * 64]);
    }
    #pragma unroll
    for (int i = 0; i < 8; i++) {
      int R0 = w * 64 + i * 8;
      int row = R0 + srow;
      int cg = sc ^ (row & 7);
      gload_lds16(Bt + (size_t)row * 256 + k0 + cg * 8, &Bs[R0 * 64]);
    }
    __syncthreads();
    #pragma unroll
    for (int kk = 0; kk < 2; kk++) {
      half8 af[4], bf[4];
      #pragma unroll
      for (int t = 0; t < 4; t++) {
        int rr = t * 16 + r;
        af[t] = *(const half8*)&As[rr * 64 + (((kk * 4 + q) ^ (rr & 7)) << 3)];
      }
      #pragma unroll
      for (int t = 0; t < 4; t++) {
        int rr = nh + t * 16 + r;
        bf[t] = *(const half8*)&Bs[rr * 64 + (((kk * 4 + q) ^ (rr & 7)) << 3)];
      }
      #pragma unroll
      for (int ti = 0; ti < 4; ti++)
        #pragma unroll
        for (int tj = 0; tj < 4; tj++)
          acc[ti][tj] = MFMA16(af[ti], bf[tj], acc[ti][tj]);
    }
  }

  float gv[4], bv[4];
  #pragma unroll
  for (int tj = 0; tj < 4; tj++) {
    int col = nh + tj * 16 + r;
    gv[tj] = gamma[col];
    bv[tj] = beta[col];
  }
  #pragma unroll
  for (int ti = 0; ti < 4; ti++) {
    #pragma unroll
    for (int i = 0; i < 4; i++) {
      int row = ti * 16 + q * 4 + i;
      float s = 0.f, ss = 0.f;
      #pragma unroll
      for (int tj = 0; tj < 4; tj++) {
        int col = nh + tj * 16 + r;
        float v = acc[ti][tj][i] + bias[col]
                + (float)res[(size_t)(m0 + row) * 256 + col];
        acc[ti][tj][i] = v;
        s += v;
        ss += v * v;
      }
      #pragma unroll
      for (int off = 1; off < 16; off <<= 1) {
        s  += __shfl_xor(s, off);
        ss += __shfl_xor(ss, off);
      }
      if (r == 0) { sSum[w][row] = s; sSq[w][row] = ss; }
    }
  }
  __syncthreads();
  if (threadIdx.x < 64) {
    int row = threadIdx.x;
    float s  = sSum[0][row] + sSum[1][row] + sSum[2][row] + sSum[3][row];
    float ss = sSq[0][row] + sSq[1][row] + sSq[2][row] + sSq[3][row];
    float mean = s * (1.f / 256.f);
    float var  = ss * (1.f / 256.f) - mean * mean;
    sMR[row][0] = mean;
    sMR[row][1] = rsqrtf(var + 1e-5f);
  }
  __syncthreads();
  #pragma unroll
  for (int ti = 0; ti < 4; ti++) {
    #pragma unroll
    for (int i = 0; i < 4; i++) {
      int row = ti * 16 + q * 4 + i;
      float mean = sMR[row][0], rstd = sMR[row][1];
      #pragma unroll
      for (int tj = 0; tj < 4; tj++) {
        int col = nh + tj * 16 + r;
        outh[(size_t)(m0 + row) * 256 + col] =
            (half_t)((acc[ti][tj][i] - mean) * rstd * gv[tj] + bv[tj]);
      }
    }
  }
}

// ---------------- fp16-gather aggregation (HC=256, H=4, fp16 acc, ELU) ----------------
__global__ __launch_bounds__(256) void k_agg_f16(
    const half_t* __restrict__ h, const float* __restrict__ es,
    const float* __restrict__ ed, const float* __restrict__ bias,
    const int* __restrict__ rowptr, const int* __restrict__ col,
    half_t* __restrict__ outh)
{
  int lane = threadIdx.x & 63;
  int g = lane >> 4, li = lane & 15;
  int n = blockIdx.x * 4 + (threadIdx.x >> 6);
  int cbase = li * 16;
  int hl = li >> 2;
  float edn = ed[(size_t)n * 4 + hl];
  int j0 = rowptr[n], j1 = rowptr[n + 1];
  const half_t* hb = h + cbase;

  float sum0 = 0.f, sum1 = 0.f;
  half8 acc0[2], acc1[2];
  #pragma unroll
  for (int i = 0; i < 2; i++) {
    acc0[i] = half8{0, 0, 0, 0, 0, 0, 0, 0};
    acc1[i] = half8{0, 0, 0, 0, 0, 0, 0, 0};
  }
  for (int j = j0 + g; j < j1; j += 8) {
    int jb = j + 4;
    int s0 = col[j];
    int s1 = col[(jb < j1) ? jb : j];
    float e0 = es[(size_t)s0 * 4 + hl] + edn;
    e0 = fmaxf(e0, 0.2f * e0);
    float e1 = es[(size_t)s1 * 4 + hl] + edn;
    e1 = fmaxf(e1, 0.2f * e1);
    e1 = (jb < j1) ? e1 : -1e30f;
    const half_t* hp0 = hb + (size_t)s0 * 256;
    const half_t* hp1 = hb + (size_t)s1 * 256;
    float p0 = exp2f(e0 * 1.44269504f - 8.65617025f);
    float p1 = exp2f(e1 * 1.44269504f - 8.65617025f);
    sum0 += p0; sum1 += p1;
    half_t q0 = (half_t)p0, q1 = (half_t)p1;
    half8 pv0 = {q0, q0, q0, q0, q0, q0, q0, q0};
    half8 pv1 = {q1, q1, q1, q1, q1, q1, q1, q1};
    #pragma unroll
    for (int i = 0; i < 2; i++) {
      half8 v0 = *(const half8*)(hp0 + i * 8);
      half8 v1 = *(const half8*)(hp1 + i * 8);
      acc0[i] += pv0 * v0;
      acc1[i] += pv1 * v1;
    }
  }
  float sum = sum0 + sum1;
  sum += __shfl_xor(sum, 16);
  sum += __shfl_xor(sum, 32);
  float av[16];
  #pragma unroll
  for (int i = 0; i < 16; i++) {
    av[i] = (float)acc0[i >> 3][i & 7] + (float)acc1[i >> 3][i & 7];
    av[i] += __shfl_xor(av[i], 16);
    av[i] += __shfl_xor(av[i], 32);
  }
  float inv = 1.f / sum;
  if (g == 0) {
    size_t obase = (size_t)n * 256 + cbase;
    #pragma unroll
    for (int p8 = 0; p8 < 2; p8++) {
      half8 hv;
      #pragma unroll
      for (int i = 0; i < 8; i++) {
        float t = av[p8 * 8 + i] * inv + bias[cbase + p8 * 8 + i];
        t = (t > 0.f) ? t : __expf(t) - 1.f;     // jax.nn.elu
        hv[i] = (half_t)t;
      }
      *(half8*)(outh + obase + p8 * 8) = hv;
    }
  }
}

// ---------------- fp8-gather aggregation (HC=256, H=4, ELU) ----------------
__global__ __launch_bounds__(256) void k_agg_fp8(
    const unsigned char* __restrict__ hq, const float* __restrict__ es,
    const float* __restrict__ ed, const float* __restrict__ bias,
    const int* __restrict__ rowptr, const int* __restrict__ col,
    half_t* __restrict__ outh)
{
  int lane = threadIdx.x & 63;
  int g = lane >> 4, li = lane & 15;
  int n = blockIdx.x * 4 + (threadIdx.x >> 6);
  int cbase = li * 16;
  int hl = li >> 2;
  float edn = ed[(size_t)n * 4 + hl];
  int j0 = rowptr[n], j1 = rowptr[n + 1];
  const unsigned char* hb = hq + cbase;

  float sum0 = 0.f, sum1 = 0.f;
  half2v a0[8], a1[8];
  #pragma unroll
  for (int i = 0; i < 8; i++) { a0[i] = half2v{0, 0}; a1[i] = half2v{0, 0}; }

  for (int j = j0 + g; j < j1; j += 8) {
    int jb = j + 4;
    int s0 = col[j];
    int s1 = col[(jb < j1) ? jb : j];
    float e0 = es[(size_t)s0 * 4 + hl] + edn;
    e0 = fmaxf(e0, 0.2f * e0);
    float e1 = es[(size_t)s1 * 4 + hl] + edn;
    e1 = fmaxf(e1, 0.2f * e1);
    e1 = (jb < j1) ? e1 : -1e30f;
    int4 d0 = *(const int4*)(hb + (size_t)s0 * 256);
    int4 d1 = *(const int4*)(hb + (size_t)s1 * 256);
    float p0 = exp2f(e0 * 1.44269504f - 8.65617025f);
    float p1 = exp2f(e1 * 1.44269504f - 8.65617025f);
    sum0 += p0; sum1 += p1;
    half_t q0 = (half_t)p0, q1 = (half_t)p1;
    half2v pv0 = {q0, q0}, pv1 = {q1, q1};
    fp8x4_fma(d0.x, pv0, &a0[0]); fp8x4_fma(d0.y, pv0, &a0[2]);
    fp8x4_fma(d0.z, pv0, &a0[4]); fp8x4_fma(d0.w, pv0, &a0[6]);
    fp8x4_fma(d1.x, pv1, &a1[0]); fp8x4_fma(d1.y, pv1, &a1[2]);
    fp8x4_fma(d1.z, pv1, &a1[4]); fp8x4_fma(d1.w, pv1, &a1[6]);
  }

  float sum = sum0 + sum1;
  sum += __shfl_xor(sum, 16);
  sum += __shfl_xor(sum, 32);
  float av[16];
  #pragma unroll
  for (int i = 0; i < 16; i++) {
    av[i] = (float)a0[i >> 1][i & 1] + (float)a1[i >> 1][i & 1];
    av[i] += __shfl_xor(av[i], 16);
    av[i] += __shfl_xor(av[i], 32);
  }
  float inv = 1.f / sum;
  if (g == 0) {
    size_t obase = (size_t)n * 256 + cbase;
    #pragma unroll
    for (int p8 = 0; p8 < 2; p8++) {
      half8 hv;
      #pragma unroll
      for (int i = 0; i < 8; i++) {
        float t = av[p8 * 8 + i] * inv + bias[cbase + p8 * 8 + i];
        t = (t > 0.f) ? t : __expf(t) - 1.f;
        hv[i] = (half_t)t;
      }
      *(half8*)(outh + obase + p8 * 8) = hv;
    }
  }
}

// ---------------- fp16-gather aggregation (GAT3: HC=128, H=1, fp32 acc) ----------------
__global__ __launch_bounds__(256) void k_agg3(
    const half_t* __restrict__ h, const float* __restrict__ es,
    const float* __restrict__ ed, const float* __restrict__ bias,
    const int* __restrict__ rowptr, const int* __restrict__ col,
    float* __restrict__ outf)
{
  constexpr int VPT = 8;
  int lane = threadIdx.x & 63;
  int g = lane >> 4, li = lane & 15;
  int n = blockIdx.x * 4 + (threadIdx.x >> 6);
  int cbase = li * VPT;
  float edn = ed[n];
  int j0 = rowptr[n], j1 = rowptr[n + 1];
  const half_t* hb = h + cbase;

  float sum0 = 0.f, sum1 = 0.f;
  float acc0[VPT], acc1[VPT];
  #pragma unroll
  for (int i = 0; i < VPT; i++) { acc0[i] = 0.f; acc1[i] = 0.f; }
  for (int j = j0 + g; j < j1; j += 8) {
    int jb = j + 4;
    int s0 = col[j];
    int s1 = col[(jb < j1) ? jb : j];
    float e0 = es[s0] + edn;
    e0 = fmaxf(e0, 0.2f * e0);
    float e1 = es[s1] + edn;
    e1 = fmaxf(e1, 0.2f * e1);
    e1 = (jb < j1) ? e1 : -1e30f;
    const half_t* hp0 = hb + (size_t)s0 * 128;
    const half_t* hp1 = hb + (size_t)s1 * 128;
    float p0 = __expf(e0), p1 = __expf(e1);
    sum0 += p0; sum1 += p1;
    half8 v0 = *(const half8*)hp0;
    half8 v1 = *(const half8*)hp1;
    #pragma unroll
    for (int i = 0; i < 8; i++) {
      acc0[i] += p0 * (float)v0[i];
      acc1[i] += p1 * (float)v1[i];
    }
  }
  float sum = sum0 + sum1;
  sum += __shfl_xor(sum, 16);
  sum += __shfl_xor(sum, 32);
  float av[VPT];
  #pragma unroll
  for (int i = 0; i < VPT; i++) {
    av[i] = acc0[i] + acc1[i];
    av[i] += __shfl_xor(av[i], 16);
    av[i] += __shfl_xor(av[i], 32);
  }
  float inv = 1.f / sum;
  if (g == 0) {
    size_t obase = (size_t)n * 128 + cbase;
    #pragma unroll
    for (int p4 = 0; p4 < 2; p4++) {
      float4 fv = {av[p4 * 4] * inv + bias[cbase + p4 * 4],
                   av[p4 * 4 + 1] * inv + bias[cbase + p4 * 4 + 1],
                   av[p4 * 4 + 2] * inv + bias[cbase + p4 * 4 + 2],
                   av[p4 * 4 + 3] * inv + bias[cbase + p4 * 4 + 3]};
      *(float4*)(outf + obase + p4 * 4) = fv;
    }
  }
}

// ---------------- MHA core (R0 known-good: 64-key tiles, 25 KB LDS) ----------------
__global__ __launch_bounds__(256) void k_attn(
    const half_t* __restrict__ qk, const half_t* __restrict__ vt,
    half_t* __restrict__ o)
{
  __shared__ __align__(16) half_t Kt[64 * 64];
  __shared__ __align__(16) half_t Vt[64 * 64];
  __shared__ __align__(16) half_t Pb[4][16][72];

  int pair = blockIdx.x;
  int b = pair >> 2, hh = pair & 3;
  int q0 = blockIdx.y * 64;
  int w = threadIdx.x >> 6, lane = threadIdx.x & 63;
  int cc = lane & 15, qq = lane >> 4;

  const half_t* Qp = qk + ((size_t)(b * NPG_ + q0 + w * 16 + cc) * 512 + hh * 64);
  half8 qa0 = *(const half8*)(Qp + qq * 8);
  half8 qa1 = *(const half8*)(Qp + 32 + qq * 8);

  f32x4 oacc[4];
  #pragma unroll
  for (int t = 0; t < 4; t++) oacc[t] = f32x4{0.f, 0.f, 0.f, 0.f};
  float rs = 0.f;

  const half_t* kb = qk + ((size_t)(b * NPG_) * 512 + 256 + hh * 64);
  const half_t* vb = vt + ((size_t)(hh * 64) * 32768 + b * NPG_);

  int krow = lane >> 3, ksl = lane & 7;

  for (int kt = 0; kt < 8; kt++) {
    __syncthreads();
    #pragma unroll
    for (int i = 0; i < 2; i++) {
      int R = w * 16 + i * 8;
      int kr = R + krow;
      gload_lds16(kb + (size_t)(kt * 64 + kr) * 512 + ((ksl ^ (kr & 7)) * 8),
                  &Kt[R * 64]);
      gload_lds16(vb + (size_t)kr * 32768 + kt * 64 + ((ksl ^ (kr & 7)) * 8),
                  &Vt[R * 64]);
    }
    __syncthreads();

    #pragma unroll
    for (int mt = 0; mt < 4; mt++) {
      int key = mt * 16 + cc;
      half8 k0 = *(const half8*)&Kt[key * 64 + ((qq ^ (key & 7)) << 3)];
      half8 k1 = *(const half8*)&Kt[key * 64 + (((qq + 4) ^ (key & 7)) << 3)];
      f32x4 s = f32x4{0.f, 0.f, 0.f, 0.f};
      s = MFMA16(k0, qa0, s);
      s = MFMA16(k1, qa1, s);
      half4v ph;
      #pragma unroll
      for (int i = 0; i < 4; i++) {
        float p = exp2f(s[i] * 0.180336886f - 11.54156033f);
        rs += p;
        ph[i] = (half_t)p;
      }
      *(half4v*)&Pb[w][cc][mt * 16 + qq * 4] = ph;
    }

    #pragma unroll
    for (int kc = 0; kc < 2; kc++) {
      half8 a = *(const half8*)&Pb[w][cc][kc * 32 + qq * 8];
      #pragma unroll
      for (int nt = 0; nt < 4; nt++) {
        int d = nt * 16 + cc;
        half8 bb = *(const half8*)&Vt[d * 64 + (((kc * 4 + qq) ^ (d & 7)) << 3)];
        oacc[nt] = MFMA16(a, bb, oacc[nt]);
      }
    }
  }

  rs += __shfl_xor(rs, 16);
  rs += __shfl_xor(rs, 32);
  #pragma unroll
  for (int i = 0; i < 4; i++) {
    float rsv = __shfl(rs, qq * 4 + i);
    float inv = 1.f / rsv;
    int node = b * NPG_ + q0 + w * 16 + qq * 4 + i;
    #pragma unroll
    for (int nt = 0; nt < 4; nt++)
      o[(size_t)node * 256 + hh * 64 + nt * 16 + cc] = (half_t)(oacc[nt][i] * inv);
  }
}

// ---------------- host ----------------
extern "C" void kernel_launch(void* const* d_in, const int* in_sizes, int n_in,
                              void* d_out, int out_size, void* d_ws, size_t ws_size,
                              hipStream_t stream)
{
  const float* x    = (const float*)d_in[0];
  const int*   ei   = (const int*)d_in[1];
  const float* W1   = (const float*)d_in[3];
  const float* aS1  = (const float*)d_in[4];
  const float* aD1  = (const float*)d_in[5];
  const float* b1   = (const float*)d_in[6];
  const float* W2   = (const float*)d_in[7];
  const float* aS2  = (const float*)d_in[8];
  const float* aD2  = (const float*)d_in[9];
  const float* b2   = (const float*)d_in[10];
  const float* W3   = (const float*)d_in[11];
  const float* aS3  = (const float*)d_in[12];
  const float* aD3  = (const float*)d_in[13];
  const float* b3   = (const float*)d_in[14];
  const float* Wi   = (const float*)d_in[15];
  const float* bi   = (const float*)d_in[16];
  const float* Wo   = (const float*)d_in[17];
  const float* bo   = (const float*)d_in[18];
  const float* gam  = (const float*)d_in[19];
  const float* bet  = (const float*)d_in[20];
  float* out = (float*)d_out;
  const int N = N_NODES;
  int E = in_sizes[1] / 2;

  char* ws = (char*)d_ws;
  size_t off = 0;
  auto alloc = [&](size_t bytes) -> void* {
    void* p = ws + off;
    off = (off + bytes + 255) & ~(size_t)255;
    return p;
  };
  half_t* x_h    = (half_t*)alloc((size_t)N * 128 * 2);
  half_t* h_h    = (half_t*)alloc((size_t)N * 256 * 2);   // h1 / h3 (fp16)
  unsigned char* hq = (unsigned char*)alloc((size_t)N * 256);  // h2 (fp8)
  half_t* x1_h   = (half_t*)alloc((size_t)N * 256 * 2);
  half_t* x2_h   = (half_t*)alloc((size_t)N * 256 * 2);
  half_t* qk_h   = (half_t*)alloc((size_t)N * 512 * 2);
  half_t* vt_h   = (half_t*)alloc((size_t)256 * N * 2);   // V^T: [256][32768]
  half_t* o_h    = (half_t*)alloc((size_t)N * 256 * 2);
  half_t* x2a_h  = (half_t*)alloc((size_t)N * 256 * 2);
  half_t* W1t    = (half_t*)alloc(256 * 128 * 2);
  half_t* W2t    = (half_t*)alloc(256 * 256 * 2);
  half_t* W3t    = (half_t*)alloc(128 * 256 * 2);
  half_t* Wi_h   = (half_t*)alloc(768 * 256 * 2);
  half_t* Wo_h   = (half_t*)alloc(256 * 256 * 2);
  float*  es     = (float*) alloc((size_t)N * 4 * 4);
  float*  ed     = (float*) alloc((size_t)N * 4 * 4);
  int*    deg    = (int*)   alloc((size_t)N * 4);
  int*    rank   = (int*)   alloc((size_t)E * 4);
  int*    rowptr = (int*)   alloc(((size_t)N + 1) * 4);
  int*    col    = (int*)   alloc((size_t)(N + E) * 4);
  int*    part   = (int*)   alloc((size_t)N * 4);
  int*    bsum   = (int*)   alloc(128 * 4);

  const int* srcE = ei;
  const int* dstE = ei + E;

  // R7/R9: deg zeroed on-stream; histogram+rank folded into k_convert tail
  hipMemsetAsync(deg, 0, (size_t)N * 4, stream);
  int convGrid = 4864 + (E + 255) / 256;
  k_convert<<<convGrid, 256, 0, stream>>>(x, x_h, W1, W1t, W2, W2t, W3, W3t,
                                          Wi, Wi_h, Wo, Wo_h, dstE, deg, rank, E);
  k_scan1<<<128, 256, 0, stream>>>(deg, part, bsum);
  // R8: scan2+scan3 fused
  k_scan23<<<128, 256, 0, stream>>>(part, bsum, rowptr, col);

  // ---- GAT1 GEMM + fused atomic-free edge scatter (R9) ----
  int eyr = (E + 1023) / 1024;
  k_gemm_gat<256, 4, false, true><<<dim3(4, N / 128 + eyr), 256, 0, stream>>>(
      x_h, W1t, h_h, nullptr, 128, aS1, aD1, es, ed,
      srcE, dstE, rowptr, rank, col, E);
  k_agg_f16<<<N / 4, 256, 0, stream>>>(h_h, es, ed, b1, rowptr, col, x1_h);

  // ---- GAT2 (fp8 gather path): h2 (fp8) + es/ed ; fp8 aggregate -> x2 ----
  k_gemm_gat<256, 4, true, false><<<dim3(4, N / 128), 256, 0, stream>>>(
      x1_h, W2t, nullptr, hq, 256, aS2, aD2, es, ed,
      nullptr, nullptr, nullptr, nullptr, nullptr, 0);
  k_agg_fp8<<<N / 4, 256, 0, stream>>>(hq, es, ed, b2, rowptr, col, x2_h);

  // ---- MHA: merged QK + V^T projections (independent -> one launch) ----
  k_gemm_qkv2<<<3072, 256, 0, stream>>>(x2_h, Wi_h, bi, qk_h, vt_h);
  k_attn<<<dim3(256, 8), 256, 0, stream>>>(qk_h, vt_h, o_h);

  // ---- Wo-GEMM + residual + LayerNorm fused -> x2a; also zeroes es/ed ----
  k_gemm_ln<<<N / 64, 256, 0, stream>>>(o_h, Wo_h, bo, x2_h, gam, bet, x2a_h, es, ed);

  // ---- GAT3 (H=1, C=128, fp16 h, fp32 acc; atomic es/ed partials) -> d_out ----
  k_gemm_gat<128, 1, false, false><<<dim3(2, N / 128), 256, 0, stream>>>(
      x2a_h, W3t, h_h, nullptr, 256, aS3, aD3, es, ed,
      nullptr, nullptr, nullptr, nullptr, nullptr, 0);
  k_agg3<<<N / 4, 256, 0, stream>>>(h_h, es, ed, b3, rowptr, col, out);
}